// Round 11
// baseline (316.742 us; speedup 1.0000x reference)
//
#include <hip/hip_runtime.h>
#include <cstdint>

// scan geometry
#define SL 2048
#define SE 2048
#define SB 2
#define SN 16
#define SC 64
#define ST 32

enum { EP_SPLIT_SILU = 1, EP_BIAS = 3, EP_PARTIAL = 4 };

typedef __attribute__((ext_vector_type(8))) short bf16x8;
typedef __attribute__((ext_vector_type(4))) float f32x4;

__device__ __forceinline__ float silu_f(float x) { return x / (1.f + __expf(-x)); }
__device__ __forceinline__ float softplus_f(float x) {
    return (x > 20.f) ? x : log1pf(__expf(x));
}
__device__ __forceinline__ ushort f2bf(float f) {
    union { float f; unsigned u; } a; a.f = f;
    unsigned r = a.u + 0x7fff + ((a.u >> 16) & 1);
    return (ushort)(r >> 16);
}
__device__ __forceinline__ float bf2f(ushort u) {
    union { float f; unsigned u; } a; a.u = ((unsigned)u) << 16;
    return a.f;
}
__device__ __forceinline__ void gload16(const void* g, void* l) {
    __builtin_amdgcn_global_load_lds(
        (const __attribute__((address_space(1))) unsigned int*)g,
        (__attribute__((address_space(3))) unsigned int*)l, 16, 0, 0);
}

// ---- shared 128x128 bf16 MFMA GEMM body, BK=64, SINGLE 32KB LDS buffer,
// m97 structure: {stage; barrier; MFMA; barrier} per K-step; occupancy from
// ~5 co-resident blocks/CU provides the latency hiding (m114 mechanism).
template <int MODE>
__device__ __forceinline__ void gemm_body(
    const ushort* __restrict__ A, const ushort* __restrict__ Bt,
    float* __restrict__ C, const float* __restrict__ bias,
    float* __restrict__ out2, int M, int N, int K, int Esplit, int KS)
{
    __shared__ ushort As[128 * 64];
    __shared__ ushort Bs[128 * 64];
    const int tid = threadIdx.x;
    const int w = tid >> 6, l = tid & 63;
    const int wr = w >> 1, wc = w & 1;
    const int m0 = blockIdx.y * 128, n0 = blockIdx.x * 128;
    const int z = blockIdx.z;
    const int kbeg = z * KS;
    const int nt = KS / 64;
    const int srow = l >> 3, scol = (l & 7) * 8;
    const int fr = l & 15, kc = (l >> 4) * 8;

    f32x4 acc[4][4];
#pragma unroll
    for (int m = 0; m < 4; m++)
#pragma unroll
        for (int n = 0; n < 4; n++) acc[m][n] = (f32x4)(0.f);

    for (int t = 0; t < nt; t++) {
        const int k0 = kbeg + t * 64;
#pragma unroll
        for (int r = 0; r < 4; r++) {
            const int row = r * 32 + w * 8 + srow;
            int brow = n0 + row; if (brow > N - 1) brow = N - 1;
            gload16(A + (size_t)(m0 + row) * K + k0 + scol,
                    &As[r * 2048 + w * 512]);
            gload16(Bt + (size_t)brow * K + k0 + scol,
                    &Bs[r * 2048 + w * 512]);
        }
        __syncthreads();
#pragma unroll
        for (int kk = 0; kk < 64; kk += 32) {
            bf16x8 af[4], bfr[4];
#pragma unroll
            for (int m = 0; m < 4; m++)
                af[m] = *(const bf16x8*)&As[(wr * 64 + m * 16 + fr) * 64 + kk + kc];
#pragma unroll
            for (int n = 0; n < 4; n++)
                bfr[n] = *(const bf16x8*)&Bs[(wc * 64 + n * 16 + fr) * 64 + kk + kc];
#pragma unroll
            for (int m = 0; m < 4; m++)
#pragma unroll
                for (int n = 0; n < 4; n++)
                    acc[m][n] = __builtin_amdgcn_mfma_f32_16x16x32_bf16(
                        af[m], bfr[n], acc[m][n], 0, 0, 0);
        }
        __syncthreads();
    }

    const int cr = (l >> 4) * 4, cc = l & 15;
    float* pbase = C + (size_t)z * M * N;
#pragma unroll
    for (int m = 0; m < 4; m++) {
#pragma unroll
        for (int j = 0; j < 4; j++) {
            const int row = m0 + wr * 64 + m * 16 + cr + j;
#pragma unroll
            for (int n = 0; n < 4; n++) {
                const int col = n0 + wc * 64 + n * 16 + cc;
                float v = acc[m][n][j];
                if (MODE == EP_SPLIT_SILU) {
                    v += bias[col];
                    if (col < Esplit)
                        C[(size_t)row * Esplit + col] = v;
                    else
                        out2[(size_t)row * Esplit + (col - Esplit)] = silu_f(v);
                } else if (MODE == EP_BIAS) {
                    C[(size_t)row * N + col] = v + bias[col];
                } else {  // EP_PARTIAL
                    if (col < N) pbase[(size_t)row * N + col] = v;
                }
            }
        }
    }
}

__global__ __launch_bounds__(256) void g1_gemm(
    const ushort* __restrict__ A, const ushort* __restrict__ Bt,
    float* __restrict__ C, const float* __restrict__ bias,
    float* __restrict__ out2, int M, int N, int K, int Esplit, int KS)
{ gemm_body<EP_SPLIT_SILU>(A, Bt, C, bias, out2, M, N, K, Esplit, KS); }

__global__ __launch_bounds__(256) void g3_gemm(
    const ushort* __restrict__ A, const ushort* __restrict__ Bt,
    float* __restrict__ C, int M, int N, int K, int KS)
{ gemm_body<EP_PARTIAL>(A, Bt, C, nullptr, nullptr, M, N, K, 0, KS); }

__global__ __launch_bounds__(256) void g6_gemm(
    const ushort* __restrict__ A, const ushort* __restrict__ Bt,
    float* __restrict__ C, const float* __restrict__ bias,
    int M, int N, int K, int KS)
{ gemm_body<EP_BIAS>(A, Bt, C, bias, nullptr, M, N, K, 0, KS); }

// ---- GEMM4: K=128, single-buffer; pure GEMM -> bf16 raw (v + bias) ----
__global__ __launch_bounds__(256) void g4_gemm(
    const ushort* __restrict__ A, const ushort* __restrict__ Bt,
    ushort* __restrict__ draw, const float* __restrict__ bias, int M, int N)
{
    __shared__ ushort As[128 * 64];
    __shared__ ushort Bs[128 * 64];
    const int tid = threadIdx.x;
    const int w = tid >> 6, l = tid & 63;
    const int wr = w >> 1, wc = w & 1;
    const int m0 = blockIdx.y * 128, n0 = blockIdx.x * 128;
    const int srow = l >> 3, scol = (l & 7) * 8;
    const int K = 128;

    f32x4 acc[4][4];
#pragma unroll
    for (int m = 0; m < 4; m++)
#pragma unroll
        for (int n = 0; n < 4; n++) acc[m][n] = (f32x4)(0.f);

    const int fr = l & 15, kc = (l >> 4) * 8;
#pragma unroll
    for (int t = 0; t < 2; t++) {
        const int k0 = t * 64;
#pragma unroll
        for (int r = 0; r < 4; r++) {
            const int row = r * 32 + w * 8 + srow;
            gload16(A + (size_t)(m0 + row) * K + k0 + scol, &As[r * 2048 + w * 512]);
            gload16(Bt + (size_t)(n0 + row) * K + k0 + scol, &Bs[r * 2048 + w * 512]);
        }
        __syncthreads();
#pragma unroll
        for (int kk = 0; kk < 64; kk += 32) {
            bf16x8 af[4], bfr[4];
#pragma unroll
            for (int m = 0; m < 4; m++)
                af[m] = *(const bf16x8*)&As[(wr * 64 + m * 16 + fr) * 64 + kk + kc];
#pragma unroll
            for (int n = 0; n < 4; n++)
                bfr[n] = *(const bf16x8*)&Bs[(wc * 64 + n * 16 + fr) * 64 + kk + kc];
#pragma unroll
            for (int m = 0; m < 4; m++)
#pragma unroll
                for (int n = 0; n < 4; n++)
                    acc[m][n] = __builtin_amdgcn_mfma_f32_16x16x32_bf16(
                        af[m], bfr[n], acc[m][n], 0, 0, 0);
        }
        __syncthreads();
    }

    const int cr = (l >> 4) * 4, cc = l & 15;
#pragma unroll
    for (int m = 0; m < 4; m++) {
#pragma unroll
        for (int j = 0; j < 4; j++) {
            const int row = m0 + wr * 64 + m * 16 + cr + j;
#pragma unroll
            for (int n = 0; n < 4; n++) {
                const int col = n0 + wc * 64 + n * 16 + cc;
                draw[(size_t)row * N + col] = f2bf(acc[m][n][j] + bias[col]);
            }
        }
    }
}

// Reduce split-K partials -> proj fp32; also emit dt columns (<128) as bf16.
__global__ __launch_bounds__(256) void gemm3_reduce(
    const float* __restrict__ Pp, float* __restrict__ proj,
    ushort* __restrict__ dtbf, int M, int N, int Z)
{
    const size_t g = (size_t)blockIdx.x * 256 + threadIdx.x;
    const size_t tot = (size_t)M * N;
    if (g >= tot) return;
    float s = 0.f;
    for (int z = 0; z < Z; z++) s += Pp[(size_t)z * tot + g];
    proj[g] = s;
    const int col = (int)(g % N);
    if (col < 128) {
        const size_t row = g / N;
        dtbf[row * 128 + col] = f2bf(s);
    }
}

// fp32 -> bf16 copy (vectorized)
__global__ __launch_bounds__(256) void f2bf_vec(
    const float* __restrict__ in, ushort* __restrict__ out, size_t n4)
{
    for (size_t i = (size_t)blockIdx.x * 256 + threadIdx.x; i < n4;
         i += (size_t)gridDim.x * 256) {
        float4 v = ((const float4*)in)[i];
        ushort4 o;
        o.x = f2bf(v.x); o.y = f2bf(v.y); o.z = f2bf(v.z); o.w = f2bf(v.w);
        ((ushort4*)out)[i] = o;
    }
}

// W (R x Ccols) fp32 -> Wt (Ccols x R) bf16, tiled transpose
__global__ __launch_bounds__(256) void f2bf_transpose(
    const float* __restrict__ W, ushort* __restrict__ Wt, int R, int Ccols)
{
    __shared__ float tile[32][33];
    const int bc = blockIdx.x * 32, br = blockIdx.y * 32;
    const int tx = threadIdx.x & 31, ty = threadIdx.x >> 5;
    for (int i = ty; i < 32; i += 8)
        tile[i][tx] = W[(size_t)(br + i) * Ccols + bc + tx];
    __syncthreads();
    for (int i = ty; i < 32; i += 8)
        Wt[(size_t)(bc + i) * R + br + tx] = f2bf(tile[tx][i]);
}

// Depthwise causal conv (K=4) + bias + SiLU; 4 ch/thread; bf16 output only.
__global__ __launch_bounds__(256) void conv_silu4(
    const float* __restrict__ xin, const float* __restrict__ w,
    const float* __restrict__ cb, ushort* __restrict__ xobf,
    int Ln, int En, size_t total4)
{
    const int Eq = En >> 2;
    for (size_t idx = (size_t)blockIdx.x * 256 + threadIdx.x; idx < total4;
         idx += (size_t)gridDim.x * 256) {
        const int e4 = (int)(idx % Eq);
        const size_t row = idx / Eq;
        const int l = (int)(row % Ln);
        float4 acc = ((const float4*)cb)[e4];
        const float4 w0 = ((const float4*)w)[e4 * 4 + 0];
        const float4 w1 = ((const float4*)w)[e4 * 4 + 1];
        const float4 w2 = ((const float4*)w)[e4 * 4 + 2];
        const float4 w3 = ((const float4*)w)[e4 * 4 + 3];
        const float wt0[4] = {w0.x, w0.y, w0.z, w0.w};
        const float wt1[4] = {w1.x, w1.y, w1.z, w1.w};
        const float wt2[4] = {w2.x, w2.y, w2.z, w2.w};
        const float wt3[4] = {w3.x, w3.y, w3.z, w3.w};
#pragma unroll
        for (int k = 0; k < 4; k++) {
            if (l - 3 + k >= 0) {
                float4 xv = ((const float4*)xin)[(row - 3 + k) * Eq + e4];
                acc.x = fmaf(wt0[k], xv.x, acc.x);
                acc.y = fmaf(wt1[k], xv.y, acc.y);
                acc.z = fmaf(wt2[k], xv.z, acc.z);
                acc.w = fmaf(wt3[k], xv.w, acc.w);
            }
        }
        ushort4 o;
        o.x = f2bf(silu_f(acc.x)); o.y = f2bf(silu_f(acc.y));
        o.z = f2bf(silu_f(acc.z)); o.w = f2bf(silu_f(acc.w));
        ((ushort4*)xobf)[idx] = o;
    }
}

// ---- Chunked parallel selective scan (delta raw bf16 + softplus here; u bf16) ----
__global__ __launch_bounds__(256) void scan_pass1(
    const ushort* __restrict__ draw, const ushort* __restrict__ u,
    const float* __restrict__ proj, const float* __restrict__ A_log,
    float* __restrict__ Pbuf, float* __restrict__ Sbuf)
{
    __shared__ float sB[ST * SN];
    const int tid = threadIdx.x;
    const int eb = blockIdx.x & 7;
    const int c  = (blockIdx.x >> 3) & (SC - 1);
    const int b  = blockIdx.x >> 9;
    const int e  = eb * 256 + tid;
    const size_t row0 = (size_t)b * SL + c * ST;

    for (int i = tid; i < ST * SN; i += 256) {
        const int tl = i >> 4, n = i & 15;
        sB[i] = proj[(row0 + tl) * 160 + 128 + n];
    }
    __syncthreads();

    float An[SN], h[SN];
    {
        const float4* Ap = (const float4*)(A_log + (size_t)e * SN);
#pragma unroll
        for (int q = 0; q < 4; q++) {
            float4 v = Ap[q];
            An[q * 4 + 0] = -expf(v.x);
            An[q * 4 + 1] = -expf(v.y);
            An[q * 4 + 2] = -expf(v.z);
            An[q * 4 + 3] = -expf(v.w);
        }
    }
#pragma unroll
    for (int n = 0; n < SN; n++) h[n] = 0.f;

    float dsum = 0.f;
    size_t idx = row0 * SE + e;
    float d = softplus_f(bf2f(draw[idx])), uu = bf2f(u[idx]);
    for (int tl = 0; tl < ST; tl++) {
        ushort dn = 0, un = 0;
        if (tl + 1 < ST) { dn = draw[idx + SE]; un = u[idx + SE]; }
        const float du = d * uu;
        dsum += d;
#pragma unroll
        for (int n = 0; n < SN; n++) {
            const float dA = __expf(d * An[n]);
            h[n] = fmaf(dA, h[n], du * sB[tl * SN + n]);
        }
        d = softplus_f(bf2f(dn)); uu = bf2f(un); idx += SE;
    }

    const size_t ob = ((((size_t)c * SB) + b) * SE + e) * SN;
#pragma unroll
    for (int q = 0; q < 4; q++) {
        float4 pv, sv;
        pv.x = __expf(An[q * 4 + 0] * dsum); sv.x = h[q * 4 + 0];
        pv.y = __expf(An[q * 4 + 1] * dsum); sv.y = h[q * 4 + 1];
        pv.z = __expf(An[q * 4 + 2] * dsum); sv.z = h[q * 4 + 2];
        pv.w = __expf(An[q * 4 + 3] * dsum); sv.w = h[q * 4 + 3];
        *(float4*)(Pbuf + ob + q * 4) = pv;
        *(float4*)(Sbuf + ob + q * 4) = sv;
    }
}

__global__ __launch_bounds__(256) void scan_pass2(
    const float* __restrict__ Pbuf, const float* __restrict__ Sbuf,
    float* __restrict__ hinit)
{
    const size_t g = (size_t)blockIdx.x * 256 + threadIdx.x;
    const size_t stride = (size_t)SB * SE * SN;
    float h = 0.f;
    float P = Pbuf[g], S = Sbuf[g];
    for (int c = 0; c < SC; c++) {
        float Pn = 0.f, Sn = 0.f;
        if (c + 1 < SC) {
            Pn = Pbuf[(c + 1) * stride + g];
            Sn = Sbuf[(c + 1) * stride + g];
        }
        hinit[c * stride + g] = h;
        h = fmaf(P, h, S);
        P = Pn; S = Sn;
    }
}

__global__ __launch_bounds__(256) void scan_pass3(
    const ushort* __restrict__ draw, const ushort* __restrict__ u,
    const float* __restrict__ proj, const float* __restrict__ A_log,
    const float* __restrict__ Dp, const float* __restrict__ xr,
    const float* __restrict__ hinit, ushort* __restrict__ yg)
{
    __shared__ float sB[ST * SN];
    __shared__ float sC[ST * SN];
    const int tid = threadIdx.x;
    const int eb = blockIdx.x & 7;
    const int c  = (blockIdx.x >> 3) & (SC - 1);
    const int b  = blockIdx.x >> 9;
    const int e  = eb * 256 + tid;
    const size_t row0 = (size_t)b * SL + c * ST;

    for (int i = tid; i < ST * SN; i += 256) {
        const int tl = i >> 4, n = i & 15;
        sB[i] = proj[(row0 + tl) * 160 + 128 + n];
        sC[i] = proj[(row0 + tl) * 160 + 144 + n];
    }
    __syncthreads();

    float An[SN], h[SN];
    {
        const float4* Ap = (const float4*)(A_log + (size_t)e * SN);
#pragma unroll
        for (int q = 0; q < 4; q++) {
            float4 v = Ap[q];
            An[q * 4 + 0] = -expf(v.x);
            An[q * 4 + 1] = -expf(v.y);
            An[q * 4 + 2] = -expf(v.z);
            An[q * 4 + 3] = -expf(v.w);
        }
    }
    {
        const size_t ib = ((((size_t)c * SB) + b) * SE + e) * SN;
#pragma unroll
        for (int q = 0; q < 4; q++) {
            float4 v = *(const float4*)(hinit + ib + q * 4);
            h[q * 4 + 0] = v.x; h[q * 4 + 1] = v.y;
            h[q * 4 + 2] = v.z; h[q * 4 + 3] = v.w;
        }
    }
    const float De = Dp[e];

    size_t idx = row0 * SE + e;
    float d = softplus_f(bf2f(draw[idx])), uu = bf2f(u[idx]), g = xr[idx];
    for (int tl = 0; tl < ST; tl++) {
        ushort dn = 0, un = 0;
        float gn = 0.f;
        if (tl + 1 < ST) {
            dn = draw[idx + SE]; un = u[idx + SE]; gn = xr[idx + SE];
        }
        const float du = d * uu;
        float y = 0.f;
#pragma unroll
        for (int n = 0; n < SN; n++) {
            const float dA = __expf(d * An[n]);
            h[n] = fmaf(dA, h[n], du * sB[tl * SN + n]);
            y = fmaf(h[n], sC[tl * SN + n], y);
        }
        yg[idx] = f2bf((y + uu * De) * g);
        d = softplus_f(bf2f(dn)); uu = bf2f(un); g = gn; idx += SE;
    }
}

extern "C" void kernel_launch(void* const* d_in, const int* in_sizes, int n_in,
                              void* d_out, int out_size, void* d_ws, size_t ws_size,
                              hipStream_t stream)
{
    const int Bc = 2, Lc = 2048, Hc = 1024, Ec = 2048;
    const int M = Bc * Lc;      // 4096
    const int PN = 160;
    const int SKZ = 8;          // GEMM3 split-K

    const float* x        = (const float*)d_in[0];
    const float* W_in     = (const float*)d_in[1];
    const float* b_in     = (const float*)d_in[2];
    const float* conv_w   = (const float*)d_in[3];
    const float* conv_b   = (const float*)d_in[4];
    const float* x_proj_w = (const float*)d_in[5];
    const float* dt_proj_w= (const float*)d_in[6];
    const float* dt_bias  = (const float*)d_in[7];
    const float* A_log    = (const float*)d_in[8];
    const float* D_param  = (const float*)d_in[9];
    const float* W_out    = (const float*)d_in[10];
    const float* b_out    = (const float*)d_in[11];
    float* out = (float*)d_out;

    float* ws = (float*)d_ws;
    const size_t ME = (size_t)M * Ec;            // 8,388,608 floats
    const size_t PS = (size_t)SB * SE * SC * SN; // 4,194,304 floats

    // region map (floats):
    float* xc_raw = ws;                  // R0: g1 z-out (conv input) / Pp3 / P,S / ygbf
    float* xr     = xc_raw + ME;         // R1: xr gate (live through pass3)
    float* r2     = xr + ME;             // R2: W_in_t early -> xc_bf (conv out)
    float* r3     = r2 + ME;             // R3: xbf early -> draw (bf16) -> W_out_t
    float* proj   = r3 + ME;
    float* hinit  = proj + (size_t)M * PN;  // also hosts xpw_t/dtw_t/dtbf pre-pass2

    ushort* xbf    = (ushort*)r3;            // dead after g1
    ushort* W_in_t = (ushort*)r2;            // dead after g1
    ushort* xc_bf  = (ushort*)r2;            // conv bf16 out; u for g3+scans
    ushort* draw   = (ushort*)r3;            // g4 raw bf16 out (16.7MB)
    float*  Pp3    = xc_raw;                 // SKZ*M*160 = 5.24M floats
    ushort* xpw_t  = (ushort*)hinit;
    ushort* dtw_t  = (ushort*)hinit + 327680;
    ushort* dtbf   = (ushort*)hinit + 327680 + 262144;
    float*  Pbuf   = xc_raw;
    float*  Sbuf   = xc_raw + PS;
    ushort* ygbf   = (ushort*)xc_raw;
    ushort* W_out_t= (ushort*)r3;            // after pass3 (draw dead)

    // 0) dtype conversions / weight transposes
    f2bf_vec<<<1024, 256, 0, stream>>>(x, xbf, (size_t)M * Hc / 4);
    f2bf_transpose<<<dim3(2 * Ec / 32, Hc / 32), 256, 0, stream>>>(
        W_in, W_in_t, Hc, 2 * Ec);
    f2bf_transpose<<<dim3(PN / 32, Ec / 32), 256, 0, stream>>>(
        x_proj_w, xpw_t, Ec, PN);
    f2bf_transpose<<<dim3(Ec / 32, 128 / 32), 256, 0, stream>>>(
        dt_proj_w, dtw_t, 128, Ec);

    // 1) z = x @ W_in + b_in ; split -> xc_raw (fp32), silu -> xr (fp32)
    g1_gemm<<<dim3(2 * Ec / 128, M / 128, 1), 256, 0, stream>>>(
        xbf, W_in_t, xc_raw, b_in, xr, M, 2 * Ec, Hc, Ec, Hc);

    // 2) depthwise causal conv + bias + silu -> xc_bf (bf16 only)
    conv_silu4<<<2048, 256, 0, stream>>>(
        xc_raw, conv_w, conv_b, xc_bf, Lc, Ec, ME / 4);

    // 3) proj = xc @ x_proj_w : split-K bf16 MFMA + reduce (emits dt bf16 too)
    g3_gemm<<<dim3(2, M / 128, SKZ), 256, 0, stream>>>(
        xc_bf, xpw_t, Pp3, M, PN, Ec, Ec / SKZ);
    gemm3_reduce<<<(M * PN + 255) / 256, 256, 0, stream>>>(
        Pp3, proj, dtbf, M, PN, SKZ);

    // 4) draw = dt @ dt_proj_w + dt_bias (bf16 raw; softplus in scans)
    g4_gemm<<<dim3(Ec / 128, M / 128), 256, 0, stream>>>(
        dtbf, dtw_t, draw, dt_bias, M, Ec);

    // 5) chunked parallel scan; pass3 emits bf16 yg
    scan_pass1<<<SB * SC * (SE / 256), 256, 0, stream>>>(
        draw, xc_bf, proj, A_log, Pbuf, Sbuf);
    scan_pass2<<<(SB * SE * SN) / 256, 256, 0, stream>>>(Pbuf, Sbuf, hinit);
    scan_pass3<<<SB * SC * (SE / 256), 256, 0, stream>>>(
        draw, xc_bf, proj, A_log, D_param, xr, hinit, ygbf);

    // 5b) W_out (E x H) -> bf16 (H x E)  (draw dead now)
    f2bf_transpose<<<dim3(Hc / 32, Ec / 32), 256, 0, stream>>>(
        W_out, W_out_t, Ec, Hc);

    // 6) out = yg @ W_out + b_out : single pass, direct write (no split-K)
    g6_gemm<<<dim3(Hc / 128, M / 128, 1), 256, 0, stream>>>(
        ygbf, W_out_t, out, b_out, M, Hc, Ec, Ec);
}

// Round 12
// 310.799 us; speedup vs baseline: 1.0191x; 1.0191x over previous
//
#include <hip/hip_runtime.h>
#include <cstdint>

// scan geometry
#define SL 2048
#define SE 2048
#define SB 2
#define SN 16
#define SC 64
#define ST 32

enum { EP_SPLIT_SILU = 1, EP_BIAS = 3, EP_PARTIAL = 4 };

typedef __attribute__((ext_vector_type(8))) short bf16x8;
typedef __attribute__((ext_vector_type(4))) float f32x4;

__device__ __forceinline__ float silu_f(float x) { return x / (1.f + __expf(-x)); }
__device__ __forceinline__ float softplus_f(float x) {
    return (x > 20.f) ? x : log1pf(__expf(x));
}
__device__ __forceinline__ ushort f2bf(float f) {
    union { float f; unsigned u; } a; a.f = f;
    unsigned r = a.u + 0x7fff + ((a.u >> 16) & 1);
    return (ushort)(r >> 16);
}
__device__ __forceinline__ float bf2f(ushort u) {
    union { float f; unsigned u; } a; a.u = ((unsigned)u) << 16;
    return a.f;
}
__device__ __forceinline__ void gload16(const void* g, void* l) {
    __builtin_amdgcn_global_load_lds(
        (const __attribute__((address_space(1))) unsigned int*)g,
        (__attribute__((address_space(3))) unsigned int*)l, 16, 0, 0);
}

// ---- 256x256 bf16 MFMA GEMM, BK=32, dbuf, COUNTED-vmcnt pipeline (T4).
// Loads for tile t+1 stay in flight across the barrier; each wave waits only
// its own tile-t loads (vmcnt(4)), then raw s_barrier makes it collective.
template <int MODE>
__global__ __launch_bounds__(512, 1) void hgemm256c(
    const ushort* __restrict__ A, const ushort* __restrict__ Bt,
    float* __restrict__ C, const float* __restrict__ bias,
    float* __restrict__ out2, int M, int N, int K, int Esplit, int KS)
{
    __shared__ ushort As[2][256 * 32];
    __shared__ ushort Bs[2][256 * 32];
    const int tid = threadIdx.x;
    const int w = tid >> 6, l = tid & 63;
    const int wr = w >> 2, wc = w & 3;          // 2 x 4 wave grid
    const int m0 = blockIdx.y * 256, n0 = blockIdx.x * 256;
    const int z = blockIdx.z;
    const int kbeg = z * KS;
    const int nt = KS / 32;
    const int srow = l >> 2;                    // 0..15
    const int scol = (l & 3) * 8;               // ushort k-offset

    f32x4 acc[8][4];
#pragma unroll
    for (int m = 0; m < 8; m++)
#pragma unroll
        for (int n = 0; n < 4; n++) acc[m][n] = (f32x4)(0.f);

    auto stage = [&](int buf, int t) {
        const int k0 = kbeg + t * 32;
#pragma unroll
        for (int r = 0; r < 2; r++) {
            const int row = w * 32 + r * 16 + srow;
            int brow = n0 + row; if (brow > N - 1) brow = N - 1;
            gload16(A + (size_t)(m0 + row) * K + k0 + scol,
                    &As[buf][(w * 32 + r * 16) * 32]);
            gload16(Bt + (size_t)brow * K + k0 + scol,
                    &Bs[buf][(w * 32 + r * 16) * 32]);
        }
    };

    stage(0, 0);                                 // 4 loads/thread in flight

    int cur = 0;
    const int fr = l & 15, kc = (l >> 4) * 8;
    for (int t = 0; t < nt; t++) {
        if (t + 1 < nt) {
            stage(cur ^ 1, t + 1);               // +4 loads (stay in flight)
            asm volatile("s_waitcnt vmcnt(4)" ::: "memory");  // tile-t loads done
        } else {
            asm volatile("s_waitcnt vmcnt(0)" ::: "memory");
        }
        __builtin_amdgcn_s_barrier();            // all waves' tile-t loads landed

        bf16x8 af[8], bfr[4];
#pragma unroll
        for (int m = 0; m < 8; m++)
            af[m] = *(const bf16x8*)&As[cur][(wr * 128 + m * 16 + fr) * 32 + kc];
#pragma unroll
        for (int n = 0; n < 4; n++)
            bfr[n] = *(const bf16x8*)&Bs[cur][(wc * 64 + n * 16 + fr) * 32 + kc];
#pragma unroll
        for (int m = 0; m < 8; m++)
#pragma unroll
            for (int n = 0; n < 4; n++)
                acc[m][n] = __builtin_amdgcn_mfma_f32_16x16x32_bf16(
                    af[m], bfr[n], acc[m][n], 0, 0, 0);

        __builtin_amdgcn_s_barrier();            // reads of cur done; safe to overwrite
        cur ^= 1;
    }

    const int cr = (l >> 4) * 4, cc = l & 15;
    float* pbase = C + (size_t)z * M * N;        // EP_PARTIAL
#pragma unroll
    for (int m = 0; m < 8; m++) {
#pragma unroll
        for (int j = 0; j < 4; j++) {
            const int row = m0 + wr * 128 + m * 16 + cr + j;
#pragma unroll
            for (int n = 0; n < 4; n++) {
                const int col = n0 + wc * 64 + n * 16 + cc;
                float v = acc[m][n][j];
                if (MODE == EP_SPLIT_SILU) {
                    v += bias[col];
                    if (col < Esplit)
                        C[(size_t)row * Esplit + col] = v;
                    else
                        out2[(size_t)row * Esplit + (col - Esplit)] = silu_f(v);
                } else {  // EP_PARTIAL
                    if (col < N) pbase[(size_t)row * N + col] = v;
                }
            }
        }
    }
}

__global__ __launch_bounds__(512, 1) void g1_gemm(
    const ushort* __restrict__ A, const ushort* __restrict__ Bt,
    float* __restrict__ C, const float* __restrict__ bias,
    float* __restrict__ out2, int M, int N, int K, int Esplit, int KS);
// (declaration kept distinct; defined via template wrapper below)

// ---- shared 128x128 bf16 MFMA GEMM body (g3), single 32KB buffer ----
template <int MODE>
__device__ __forceinline__ void gemm_body(
    const ushort* __restrict__ A, const ushort* __restrict__ Bt,
    float* __restrict__ C, const float* __restrict__ bias,
    float* __restrict__ out2, int M, int N, int K, int Esplit, int KS)
{
    __shared__ ushort As[128 * 64];
    __shared__ ushort Bs[128 * 64];
    const int tid = threadIdx.x;
    const int w = tid >> 6, l = tid & 63;
    const int wr = w >> 1, wc = w & 1;
    const int m0 = blockIdx.y * 128, n0 = blockIdx.x * 128;
    const int z = blockIdx.z;
    const int kbeg = z * KS;
    const int nt = KS / 64;
    const int srow = l >> 3, scol = (l & 7) * 8;
    const int fr = l & 15, kc = (l >> 4) * 8;

    f32x4 acc[4][4];
#pragma unroll
    for (int m = 0; m < 4; m++)
#pragma unroll
        for (int n = 0; n < 4; n++) acc[m][n] = (f32x4)(0.f);

    for (int t = 0; t < nt; t++) {
        const int k0 = kbeg + t * 64;
#pragma unroll
        for (int r = 0; r < 4; r++) {
            const int row = r * 32 + w * 8 + srow;
            int brow = n0 + row; if (brow > N - 1) brow = N - 1;
            gload16(A + (size_t)(m0 + row) * K + k0 + scol,
                    &As[r * 2048 + w * 512]);
            gload16(Bt + (size_t)brow * K + k0 + scol,
                    &Bs[r * 2048 + w * 512]);
        }
        __syncthreads();
#pragma unroll
        for (int kk = 0; kk < 64; kk += 32) {
            bf16x8 af[4], bfr[4];
#pragma unroll
            for (int m = 0; m < 4; m++)
                af[m] = *(const bf16x8*)&As[(wr * 64 + m * 16 + fr) * 64 + kk + kc];
#pragma unroll
            for (int n = 0; n < 4; n++)
                bfr[n] = *(const bf16x8*)&Bs[(wc * 64 + n * 16 + fr) * 64 + kk + kc];
#pragma unroll
            for (int m = 0; m < 4; m++)
#pragma unroll
                for (int n = 0; n < 4; n++)
                    acc[m][n] = __builtin_amdgcn_mfma_f32_16x16x32_bf16(
                        af[m], bfr[n], acc[m][n], 0, 0, 0);
        }
        __syncthreads();
    }

    const int cr = (l >> 4) * 4, cc = l & 15;
    float* pbase = C + (size_t)z * M * N;
#pragma unroll
    for (int m = 0; m < 4; m++) {
#pragma unroll
        for (int j = 0; j < 4; j++) {
            const int row = m0 + wr * 64 + m * 16 + cr + j;
#pragma unroll
            for (int n = 0; n < 4; n++) {
                const int col = n0 + wc * 64 + n * 16 + cc;
                float v = acc[m][n][j];
                if (MODE == EP_BIAS) {
                    C[(size_t)row * N + col] = v + bias[col];
                } else {  // EP_PARTIAL
                    if (col < N) pbase[(size_t)row * N + col] = v;
                }
            }
        }
    }
}

// Distinct names:
__global__ __launch_bounds__(512, 1) void g1_gemm256(
    const ushort* __restrict__ A, const ushort* __restrict__ Bt,
    float* __restrict__ C, const float* __restrict__ bias,
    float* __restrict__ out2, int M, int N, int K, int Esplit, int KS)
{
    // delegate to counted-vmcnt 256^2 body
    // (manual inline of hgemm256c<EP_SPLIT_SILU> semantics via direct call)
}

__global__ __launch_bounds__(256) void g3_gemm(
    const ushort* __restrict__ A, const ushort* __restrict__ Bt,
    float* __restrict__ C, int M, int N, int K, int KS)
{ gemm_body<EP_PARTIAL>(A, Bt, C, nullptr, nullptr, M, N, K, 0, KS); }

// ---- GEMM4: K=128, single-buffer; pure GEMM -> bf16 raw (v + bias) ----
__global__ __launch_bounds__(256) void g4_gemm(
    const ushort* __restrict__ A, const ushort* __restrict__ Bt,
    ushort* __restrict__ draw, const float* __restrict__ bias, int M, int N)
{
    __shared__ ushort As[128 * 64];
    __shared__ ushort Bs[128 * 64];
    const int tid = threadIdx.x;
    const int w = tid >> 6, l = tid & 63;
    const int wr = w >> 1, wc = w & 1;
    const int m0 = blockIdx.y * 128, n0 = blockIdx.x * 128;
    const int srow = l >> 3, scol = (l & 7) * 8;
    const int K = 128;

    f32x4 acc[4][4];
#pragma unroll
    for (int m = 0; m < 4; m++)
#pragma unroll
        for (int n = 0; n < 4; n++) acc[m][n] = (f32x4)(0.f);

    const int fr = l & 15, kc = (l >> 4) * 8;
#pragma unroll
    for (int t = 0; t < 2; t++) {
        const int k0 = t * 64;
#pragma unroll
        for (int r = 0; r < 4; r++) {
            const int row = r * 32 + w * 8 + srow;
            gload16(A + (size_t)(m0 + row) * K + k0 + scol, &As[r * 2048 + w * 512]);
            gload16(Bt + (size_t)(n0 + row) * K + k0 + scol, &Bs[r * 2048 + w * 512]);
        }
        __syncthreads();
#pragma unroll
        for (int kk = 0; kk < 64; kk += 32) {
            bf16x8 af[4], bfr[4];
#pragma unroll
            for (int m = 0; m < 4; m++)
                af[m] = *(const bf16x8*)&As[(wr * 64 + m * 16 + fr) * 64 + kk + kc];
#pragma unroll
            for (int n = 0; n < 4; n++)
                bfr[n] = *(const bf16x8*)&Bs[(wc * 64 + n * 16 + fr) * 64 + kk + kc];
#pragma unroll
            for (int m = 0; m < 4; m++)
#pragma unroll
                for (int n = 0; n < 4; n++)
                    acc[m][n] = __builtin_amdgcn_mfma_f32_16x16x32_bf16(
                        af[m], bfr[n], acc[m][n], 0, 0, 0);
        }
        __syncthreads();
    }

    const int cr = (l >> 4) * 4, cc = l & 15;
#pragma unroll
    for (int m = 0; m < 4; m++) {
#pragma unroll
        for (int j = 0; j < 4; j++) {
            const int row = m0 + wr * 64 + m * 16 + cr + j;
#pragma unroll
            for (int n = 0; n < 4; n++) {
                const int col = n0 + wc * 64 + n * 16 + cc;
                draw[(size_t)row * N + col] = f2bf(acc[m][n][j] + bias[col]);
            }
        }
    }
}

// Reduce split-K partials -> proj fp32; also emit dt columns (<128) as bf16.
__global__ __launch_bounds__(256) void gemm3_reduce(
    const float* __restrict__ Pp, float* __restrict__ proj,
    ushort* __restrict__ dtbf, int M, int N, int Z)
{
    const size_t g = (size_t)blockIdx.x * 256 + threadIdx.x;
    const size_t tot = (size_t)M * N;
    if (g >= tot) return;
    float s = 0.f;
    for (int z = 0; z < Z; z++) s += Pp[(size_t)z * tot + g];
    proj[g] = s;
    const int col = (int)(g % N);
    if (col < 128) {
        const size_t row = g / N;
        dtbf[row * 128 + col] = f2bf(s);
    }
}

// Reduce GEMM6 split-K(Z) partials + bias -> out fp32 (float4).
__global__ __launch_bounds__(256) void reduce6(
    const float* __restrict__ Pp, const float* __restrict__ bias,
    float* __restrict__ out, int M, int N, int Z)
{
    const size_t g = (size_t)blockIdx.x * 256 + threadIdx.x;
    const size_t tot4 = (size_t)M * N / 4;
    if (g >= tot4) return;
    const int n4 = N / 4;
    float4 s = ((const float4*)bias)[g % n4];
    for (int z = 0; z < Z; z++) {
        float4 p = ((const float4*)Pp)[z * tot4 + g];
        s.x += p.x; s.y += p.y; s.z += p.z; s.w += p.w;
    }
    ((float4*)out)[g] = s;
}

// fp32 -> bf16 copy (vectorized)
__global__ __launch_bounds__(256) void f2bf_vec(
    const float* __restrict__ in, ushort* __restrict__ out, size_t n4)
{
    for (size_t i = (size_t)blockIdx.x * 256 + threadIdx.x; i < n4;
         i += (size_t)gridDim.x * 256) {
        float4 v = ((const float4*)in)[i];
        ushort4 o;
        o.x = f2bf(v.x); o.y = f2bf(v.y); o.z = f2bf(v.z); o.w = f2bf(v.w);
        ((ushort4*)out)[i] = o;
    }
}

// W (R x Ccols) fp32 -> Wt (Ccols x R) bf16, tiled transpose
__global__ __launch_bounds__(256) void f2bf_transpose(
    const float* __restrict__ W, ushort* __restrict__ Wt, int R, int Ccols)
{
    __shared__ float tile[32][33];
    const int bc = blockIdx.x * 32, br = blockIdx.y * 32;
    const int tx = threadIdx.x & 31, ty = threadIdx.x >> 5;
    for (int i = ty; i < 32; i += 8)
        tile[i][tx] = W[(size_t)(br + i) * Ccols + bc + tx];
    __syncthreads();
    for (int i = ty; i < 32; i += 8)
        Wt[(size_t)(bc + i) * R + br + tx] = f2bf(tile[tx][i]);
}

// Depthwise causal conv (K=4) + bias + SiLU; 4 ch/thread; bf16 output only.
__global__ __launch_bounds__(256) void conv_silu4(
    const float* __restrict__ xin, const float* __restrict__ w,
    const float* __restrict__ cb, ushort* __restrict__ xobf,
    int Ln, int En, size_t total4)
{
    const int Eq = En >> 2;
    for (size_t idx = (size_t)blockIdx.x * 256 + threadIdx.x; idx < total4;
         idx += (size_t)gridDim.x * 256) {
        const int e4 = (int)(idx % Eq);
        const size_t row = idx / Eq;
        const int l = (int)(row % Ln);
        float4 acc = ((const float4*)cb)[e4];
        const float4 w0 = ((const float4*)w)[e4 * 4 + 0];
        const float4 w1 = ((const float4*)w)[e4 * 4 + 1];
        const float4 w2 = ((const float4*)w)[e4 * 4 + 2];
        const float4 w3 = ((const float4*)w)[e4 * 4 + 3];
        const float wt0[4] = {w0.x, w0.y, w0.z, w0.w};
        const float wt1[4] = {w1.x, w1.y, w1.z, w1.w};
        const float wt2[4] = {w2.x, w2.y, w2.z, w2.w};
        const float wt3[4] = {w3.x, w3.y, w3.z, w3.w};
#pragma unroll
        for (int k = 0; k < 4; k++) {
            if (l - 3 + k >= 0) {
                float4 xv = ((const float4*)xin)[(row - 3 + k) * Eq + e4];
                acc.x = fmaf(wt0[k], xv.x, acc.x);
                acc.y = fmaf(wt1[k], xv.y, acc.y);
                acc.z = fmaf(wt2[k], xv.z, acc.z);
                acc.w = fmaf(wt3[k], xv.w, acc.w);
            }
        }
        ushort4 o;
        o.x = f2bf(silu_f(acc.x)); o.y = f2bf(silu_f(acc.y));
        o.z = f2bf(silu_f(acc.z)); o.w = f2bf(silu_f(acc.w));
        ((ushort4*)xobf)[idx] = o;
    }
}

// ---- Chunked parallel selective scan (delta raw bf16 + softplus here; u bf16) ----
__global__ __launch_bounds__(256) void scan_pass1(
    const ushort* __restrict__ draw, const ushort* __restrict__ u,
    const float* __restrict__ proj, const float* __restrict__ A_log,
    float* __restrict__ Pbuf, float* __restrict__ Sbuf)
{
    __shared__ float sB[ST * SN];
    const int tid = threadIdx.x;
    const int eb = blockIdx.x & 7;
    const int c  = (blockIdx.x >> 3) & (SC - 1);
    const int b  = blockIdx.x >> 9;
    const int e  = eb * 256 + tid;
    const size_t row0 = (size_t)b * SL + c * ST;

    for (int i = tid; i < ST * SN; i += 256) {
        const int tl = i >> 4, n = i & 15;
        sB[i] = proj[(row0 + tl) * 160 + 128 + n];
    }
    __syncthreads();

    float An[SN], h[SN];
    {
        const float4* Ap = (const float4*)(A_log + (size_t)e * SN);
#pragma unroll
        for (int q = 0; q < 4; q++) {
            float4 v = Ap[q];
            An[q * 4 + 0] = -expf(v.x);
            An[q * 4 + 1] = -expf(v.y);
            An[q * 4 + 2] = -expf(v.z);
            An[q * 4 + 3] = -expf(v.w);
        }
    }
#pragma unroll
    for (int n = 0; n < SN; n++) h[n] = 0.f;

    float dsum = 0.f;
    size_t idx = row0 * SE + e;
    float d = softplus_f(bf2f(draw[idx])), uu = bf2f(u[idx]);
    for (int tl = 0; tl < ST; tl++) {
        ushort dn = 0, un = 0;
        if (tl + 1 < ST) { dn = draw[idx + SE]; un = u[idx + SE]; }
        const float du = d * uu;
        dsum += d;
#pragma unroll
        for (int n = 0; n < SN; n++) {
            const float dA = __expf(d * An[n]);
            h[n] = fmaf(dA, h[n], du * sB[tl * SN + n]);
        }
        d = softplus_f(bf2f(dn)); uu = bf2f(un); idx += SE;
    }

    const size_t ob = ((((size_t)c * SB) + b) * SE + e) * SN;
#pragma unroll
    for (int q = 0; q < 4; q++) {
        float4 pv, sv;
        pv.x = __expf(An[q * 4 + 0] * dsum); sv.x = h[q * 4 + 0];
        pv.y = __expf(An[q * 4 + 1] * dsum); sv.y = h[q * 4 + 1];
        pv.z = __expf(An[q * 4 + 2] * dsum); sv.z = h[q * 4 + 2];
        pv.w = __expf(An[q * 4 + 3] * dsum); sv.w = h[q * 4 + 3];
        *(float4*)(Pbuf + ob + q * 4) = pv;
        *(float4*)(Sbuf + ob + q * 4) = sv;
    }
}

__global__ __launch_bounds__(256) void scan_pass2(
    const float* __restrict__ Pbuf, const float* __restrict__ Sbuf,
    float* __restrict__ hinit)
{
    const size_t g = (size_t)blockIdx.x * 256 + threadIdx.x;
    const size_t stride = (size_t)SB * SE * SN;
    float h = 0.f;
    float P = Pbuf[g], S = Sbuf[g];
    for (int c = 0; c < SC; c++) {
        float Pn = 0.f, Sn = 0.f;
        if (c + 1 < SC) {
            Pn = Pbuf[(c + 1) * stride + g];
            Sn = Sbuf[(c + 1) * stride + g];
        }
        hinit[c * stride + g] = h;
        h = fmaf(P, h, S);
        P = Pn; S = Sn;
    }
}

__global__ __launch_bounds__(256) void scan_pass3(
    const ushort* __restrict__ draw, const ushort* __restrict__ u,
    const float* __restrict__ proj, const float* __restrict__ A_log,
    const float* __restrict__ Dp, const float* __restrict__ xr,
    const float* __restrict__ hinit, ushort* __restrict__ yg)
{
    __shared__ float sB[ST * SN];
    __shared__ float sC[ST * SN];
    const int tid = threadIdx.x;
    const int eb = blockIdx.x & 7;
    const int c  = (blockIdx.x >> 3) & (SC - 1);
    const int b  = blockIdx.x >> 9;
    const int e  = eb * 256 + tid;
    const size_t row0 = (size_t)b * SL + c * ST;

    for (int i = tid; i < ST * SN; i += 256) {
        const int tl = i >> 4, n = i & 15;
        sB[i] = proj[(row0 + tl) * 160 + 128 + n];
        sC[i] = proj[(row0 + tl) * 160 + 144 + n];
    }
    __syncthreads();

    float An[SN], h[SN];
    {
        const float4* Ap = (const float4*)(A_log + (size_t)e * SN);
#pragma unroll
        for (int q = 0; q < 4; q++) {
            float4 v = Ap[q];
            An[q * 4 + 0] = -expf(v.x);
            An[q * 4 + 1] = -expf(v.y);
            An[q * 4 + 2] = -expf(v.z);
            An[q * 4 + 3] = -expf(v.w);
        }
    }
    {
        const size_t ib = ((((size_t)c * SB) + b) * SE + e) * SN;
#pragma unroll
        for (int q = 0; q < 4; q++) {
            float4 v = *(const float4*)(hinit + ib + q * 4);
            h[q * 4 + 0] = v.x; h[q * 4 + 1] = v.y;
            h[q * 4 + 2] = v.z; h[q * 4 + 3] = v.w;
        }
    }
    const float De = Dp[e];

    size_t idx = row0 * SE + e;
    float d = softplus_f(bf2f(draw[idx])), uu = bf2f(u[idx]), g = xr[idx];
    for (int tl = 0; tl < ST; tl++) {
        ushort dn = 0, un = 0;
        float gn = 0.f;
        if (tl + 1 < ST) {
            dn = draw[idx + SE]; un = u[idx + SE]; gn = xr[idx + SE];
        }
        const float du = d * uu;
        float y = 0.f;
#pragma unroll
        for (int n = 0; n < SN; n++) {
            const float dA = __expf(d * An[n]);
            h[n] = fmaf(dA, h[n], du * sB[tl * SN + n]);
            y = fmaf(h[n], sC[tl * SN + n], y);
        }
        yg[idx] = f2bf((y + uu * De) * g);
        d = softplus_f(bf2f(dn)); uu = bf2f(un); g = gn; idx += SE;
    }
}

extern "C" void kernel_launch(void* const* d_in, const int* in_sizes, int n_in,
                              void* d_out, int out_size, void* d_ws, size_t ws_size,
                              hipStream_t stream)
{
    const int Bc = 2, Lc = 2048, Hc = 1024, Ec = 2048;
    const int M = Bc * Lc;      // 4096
    const int PN = 160;
    const int SKZ = 8;          // GEMM3 split-K
    const int SK6 = 4;          // GEMM6 split-K (256^2 tile -> 4x16x4 = 256 blocks)

    const float* x        = (const float*)d_in[0];
    const float* W_in     = (const float*)d_in[1];
    const float* b_in     = (const float*)d_in[2];
    const float* conv_w   = (const float*)d_in[3];
    const float* conv_b   = (const float*)d_in[4];
    const float* x_proj_w = (const float*)d_in[5];
    const float* dt_proj_w= (const float*)d_in[6];
    const float* dt_bias  = (const float*)d_in[7];
    const float* A_log    = (const float*)d_in[8];
    const float* D_param  = (const float*)d_in[9];
    const float* W_out    = (const float*)d_in[10];
    const float* b_out    = (const float*)d_in[11];
    float* out = (float*)d_out;

    float* ws = (float*)d_ws;
    const size_t ME = (size_t)M * Ec;            // 8,388,608 floats
    const size_t PS = (size_t)SB * SE * SC * SN; // 4,194,304 floats

    // region map (floats):
    float* xc_raw = ws;                  // R0: g1 z-out (conv input) / Pp3 / P,S / ygbf
    float* xr     = xc_raw + ME;         // R1: xr gate -> Pp6 (spans R1+R2) after pass3
    float* r2     = xr + ME;             // R2: W_in_t early -> xc_bf (conv out)
    float* r3     = r2 + ME;             // R3: xbf early -> draw (bf16) -> W_out_t
    float* proj   = r3 + ME;
    float* hinit  = proj + (size_t)M * PN;  // also hosts xpw_t/dtw_t/dtbf pre-pass2

    ushort* xbf    = (ushort*)r3;            // dead after g1
    ushort* W_in_t = (ushort*)r2;            // dead after g1
    ushort* xc_bf  = (ushort*)r2;            // conv bf16 out; u for g3+scans
    ushort* draw   = (ushort*)r3;            // g4 raw bf16 out (16.7MB)
    float*  Pp3    = xc_raw;                 // SKZ*M*160 = 5.24M floats
    ushort* xpw_t  = (ushort*)hinit;
    ushort* dtw_t  = (ushort*)hinit + 327680;
    ushort* dtbf   = (ushort*)hinit + 327680 + 262144;
    float*  Pbuf   = xc_raw;
    float*  Sbuf   = xc_raw + PS;
    ushort* ygbf   = (ushort*)xc_raw;
    ushort* W_out_t= (ushort*)r3;            // after pass3 (draw dead)
    float*  Pp6    = xr;                     // SK6*M*1024 = 16.78M fl = R1+R2 (both dead)

    // 0) dtype conversions / weight transposes
    f2bf_vec<<<1024, 256, 0, stream>>>(x, xbf, (size_t)M * Hc / 4);
    f2bf_transpose<<<dim3(2 * Ec / 32, Hc / 32), 256, 0, stream>>>(
        W_in, W_in_t, Hc, 2 * Ec);
    f2bf_transpose<<<dim3(PN / 32, Ec / 32), 256, 0, stream>>>(
        x_proj_w, xpw_t, Ec, PN);
    f2bf_transpose<<<dim3(Ec / 32, 128 / 32), 256, 0, stream>>>(
        dt_proj_w, dtw_t, 128, Ec);

    // 1) z = x @ W_in + b_in ; split -> xc_raw (fp32), silu -> xr (fp32)
    //    256^2 counted-vmcnt pipeline, grid 16x16 = 256 blocks (1/CU)
    hgemm256c<EP_SPLIT_SILU><<<dim3(2 * Ec / 256, M / 256, 1), 512, 0, stream>>>(
        xbf, W_in_t, xc_raw, b_in, xr, M, 2 * Ec, Hc, Ec, Hc);

    // 2) depthwise causal conv + bias + silu -> xc_bf (bf16 only)
    conv_silu4<<<2048, 256, 0, stream>>>(
        xc_raw, conv_w, conv_b, xc_bf, Lc, Ec, ME / 4);

    // 3) proj = xc @ x_proj_w : split-K bf16 MFMA + reduce (emits dt bf16 too)
    g3_gemm<<<dim3(2, M / 128, SKZ), 256, 0, stream>>>(
        xc_bf, xpw_t, Pp3, M, PN, Ec, Ec / SKZ);
    gemm3_reduce<<<(M * PN + 255) / 256, 256, 0, stream>>>(
        Pp3, proj, dtbf, M, PN, SKZ);

    // 4) draw = dt @ dt_proj_w + dt_bias (bf16 raw; softplus in scans)
    g4_gemm<<<dim3(Ec / 128, M / 128), 256, 0, stream>>>(
        dtbf, dtw_t, draw, dt_bias, M, Ec);

    // 5) chunked parallel scan; pass3 emits bf16 yg
    scan_pass1<<<SB * SC * (SE / 256), 256, 0, stream>>>(
        draw, xc_bf, proj, A_log, Pbuf, Sbuf);
    scan_pass2<<<(SB * SE * SN) / 256, 256, 0, stream>>>(Pbuf, Sbuf, hinit);
    scan_pass3<<<SB * SC * (SE / 256), 256, 0, stream>>>(
        draw, xc_bf, proj, A_log, D_param, xr, hinit, ygbf);

    // 5b) W_out (E x H) -> bf16 (H x E)  (draw dead now)
    f2bf_transpose<<<dim3(Hc / 32, Ec / 32), 256, 0, stream>>>(
        W_out, W_out_t, Ec, Hc);

    // 6) out = yg @ W_out : 256^2 counted-vmcnt, split-K=4 + bias reduce
    hgemm256c<EP_PARTIAL><<<dim3(Hc / 256, M / 256, SK6), 512, 0, stream>>>(
        ygbf, W_out_t, Pp6, nullptr, nullptr, M, Hc, Ec, 0, Ec / SK6);
    reduce6<<<(int)((size_t)M * Hc / 4 + 255) / 256, 256, 0, stream>>>(
        Pp6, b_out, out, M, Hc, SK6);
}

// Round 13
// 309.028 us; speedup vs baseline: 1.0250x; 1.0057x over previous
//
#include <hip/hip_runtime.h>
#include <cstdint>

// scan geometry
#define SL 2048
#define SE 2048
#define SB 2
#define SN 16
#define SC 64
#define ST 32

enum { EP_SPLIT_SILU = 1, EP_BIAS = 3, EP_PARTIAL = 4 };

typedef __attribute__((ext_vector_type(8))) short bf16x8;
typedef __attribute__((ext_vector_type(4))) float f32x4;

__device__ __forceinline__ float silu_f(float x) { return x / (1.f + __expf(-x)); }
__device__ __forceinline__ float softplus_f(float x) {
    return (x > 20.f) ? x : log1pf(__expf(x));
}
__device__ __forceinline__ ushort f2bf(float f) {
    union { float f; unsigned u; } a; a.f = f;
    unsigned r = a.u + 0x7fff + ((a.u >> 16) & 1);
    return (ushort)(r >> 16);
}
__device__ __forceinline__ float bf2f(ushort u) {
    union { float f; unsigned u; } a; a.u = ((unsigned)u) << 16;
    return a.f;
}
__device__ __forceinline__ void gload16(const void* g, void* l) {
    __builtin_amdgcn_global_load_lds(
        (const __attribute__((address_space(1))) unsigned int*)g,
        (__attribute__((address_space(3))) unsigned int*)l, 16, 0, 0);
}

// ---- 256x256 bf16 MFMA GEMM, BK=64, 8-phase-style interleave (T2+T3+T4+T5).
// 2 LDS slots per matrix (128 KB), 512 thr / 8 waves (2M x 4N).
// Per K-tile: 4 phases x {maybe-stage, ds_read subtile, setprio, 16 MFMA, barrier}.
// LDS XOR-swizzle kbyte ^= (row&7)<<4 on write-source and read (rule #21).
template <int MODE>
__global__ __launch_bounds__(512, 1) void hgemm8p(
    const ushort* __restrict__ A, const ushort* __restrict__ Bt,
    float* __restrict__ C, const float* __restrict__ bias,
    float* __restrict__ out2, int M, int N, int K, int Esplit, int KS)
{
    __shared__ ushort As[2][256 * 64];
    __shared__ ushort Bs[2][256 * 64];
    const int tid = threadIdx.x;
    const int w = tid >> 6, l = tid & 63;
    const int wr = w >> 2, wc = w & 3;          // 2 x 4 wave grid
    const int m0 = blockIdx.y * 256, n0 = blockIdx.x * 256;
    const int z = blockIdx.z;
    const int kbeg = z * KS;
    const int nt = KS / 64;

    // staging geometry: gload q covers rows q*64 + w*8 + (l>>3), 16B at
    // linear kbyte (l&7)*16; source k pre-swizzled: 16*((l&7)^(l>>3)).
    const int srow_w = w * 8 + (l >> 3);         // row within 64-row group
    const int skel   = 8 * ((l & 7) ^ (l >> 3)); // swizzled source k (elems)

    f32x4 acc[8][4];
#pragma unroll
    for (int m = 0; m < 8; m++)
#pragma unroll
        for (int n = 0; n < 4; n++) acc[m][n] = (f32x4)(0.f);

    auto stageA = [&](int slot, int t) {
        const int k0 = kbeg + t * 64;
#pragma unroll
        for (int q = 0; q < 4; q++) {
            const int row = q * 64 + srow_w;
            gload16(A + (size_t)(m0 + row) * K + k0 + skel,
                    &As[slot][q * 4096 + w * 512]);
        }
    };
    auto stageB = [&](int slot, int t) {
        const int k0 = kbeg + t * 64;
#pragma unroll
        for (int q = 0; q < 4; q++) {
            const int row = q * 64 + srow_w;
            gload16(Bt + (size_t)(n0 + row) * K + k0 + skel,
                    &Bs[slot][q * 4096 + w * 512]);
        }
    };

    // swizzled fragment address (ushort index): element (row, ks*32 + (l>>4)*8)
    const int fr  = l & 15;
    const int kxo = ((l >> 4) * 16);             // linear sub-kbyte
    const int swz = (l & 7) << 4;                // row&7 == l&7 for frag rows
    auto aoff = [&](int m, int ks) {
        const int row = wr * 128 + m * 16 + fr;
        return row * 64 + (((ks * 64 + kxo) ^ swz) >> 1);
    };
    auto boff = [&](int n, int ks) {
        const int row = wc * 64 + n * 16 + fr;
        return row * 64 + (((ks * 64 + kxo) ^ swz) >> 1);
    };

    // prologue: stage tile 0 into slot 0, drain, full barrier
    stageA(0, 0);
    stageB(0, 0);
    asm volatile("s_waitcnt vmcnt(0)" ::: "memory");
    __syncthreads();

    for (int t = 0; t < nt; t++) {
        const int s = t & 1;
        const bool pf = (t + 1 < nt);
        bf16x8 af[4][2], bf[2][2], bf2[2][2];

        // ---- phase 1: stage A(t+1); read af(m0-3), bf(n0-1); MFMA m0-3 x n0-1
        if (pf) stageA(s ^ 1, t + 1);
#pragma unroll
        for (int m = 0; m < 4; m++)
#pragma unroll
            for (int ks = 0; ks < 2; ks++)
                af[m][ks] = *(const bf16x8*)&As[s][aoff(m, ks)];
#pragma unroll
        for (int n = 0; n < 2; n++)
#pragma unroll
            for (int ks = 0; ks < 2; ks++)
                bf[n][ks] = *(const bf16x8*)&Bs[s][boff(n, ks)];
        __builtin_amdgcn_s_setprio(1);
#pragma unroll
        for (int m = 0; m < 4; m++)
#pragma unroll
            for (int n = 0; n < 2; n++)
#pragma unroll
                for (int ks = 0; ks < 2; ks++)
                    acc[m][n] = __builtin_amdgcn_mfma_f32_16x16x32_bf16(
                        af[m][ks], bf[n][ks], acc[m][n], 0, 0, 0);
        __builtin_amdgcn_s_setprio(0);
        __builtin_amdgcn_s_barrier();

        // ---- phase 2: stage B(t+1); read bf2(n2-3); MFMA m0-3 x n2-3 (af reused)
        if (pf) stageB(s ^ 1, t + 1);
#pragma unroll
        for (int n = 0; n < 2; n++)
#pragma unroll
            for (int ks = 0; ks < 2; ks++)
                bf2[n][ks] = *(const bf16x8*)&Bs[s][boff(2 + n, ks)];
        __builtin_amdgcn_s_setprio(1);
#pragma unroll
        for (int m = 0; m < 4; m++)
#pragma unroll
            for (int n = 0; n < 2; n++)
#pragma unroll
                for (int ks = 0; ks < 2; ks++)
                    acc[m][2 + n] = __builtin_amdgcn_mfma_f32_16x16x32_bf16(
                        af[m][ks], bf2[n][ks], acc[m][2 + n], 0, 0, 0);
        __builtin_amdgcn_s_setprio(0);
        __builtin_amdgcn_s_barrier();

        // ---- phase 3: read af(m4-7); MFMA m4-7 x n2-3 (bf2 reused)
#pragma unroll
        for (int m = 0; m < 4; m++)
#pragma unroll
            for (int ks = 0; ks < 2; ks++)
                af[m][ks] = *(const bf16x8*)&As[s][aoff(4 + m, ks)];
        __builtin_amdgcn_s_setprio(1);
#pragma unroll
        for (int m = 0; m < 4; m++)
#pragma unroll
            for (int n = 0; n < 2; n++)
#pragma unroll
                for (int ks = 0; ks < 2; ks++)
                    acc[4 + m][2 + n] = __builtin_amdgcn_mfma_f32_16x16x32_bf16(
                        af[m][ks], bf2[n][ks], acc[4 + m][2 + n], 0, 0, 0);
        __builtin_amdgcn_s_setprio(0);
        __builtin_amdgcn_s_barrier();

        // ---- phase 4: re-read bf(n0-1); MFMA m4-7 x n0-1; iteration fence
#pragma unroll
        for (int n = 0; n < 2; n++)
#pragma unroll
            for (int ks = 0; ks < 2; ks++)
                bf[n][ks] = *(const bf16x8*)&Bs[s][boff(n, ks)];
        __builtin_amdgcn_s_setprio(1);
#pragma unroll
        for (int m = 0; m < 4; m++)
#pragma unroll
            for (int n = 0; n < 2; n++)
#pragma unroll
                for (int ks = 0; ks < 2; ks++)
                    acc[4 + m][n] = __builtin_amdgcn_mfma_f32_16x16x32_bf16(
                        af[m][ks], bf[n][ks], acc[4 + m][n], 0, 0, 0);
        __builtin_amdgcn_s_setprio(0);
        // iteration fence: next tile's loads must be in LDS; __syncthreads
        // drains vmcnt(0)+lgkmcnt(0) (loads are ~3 phases old -> cheap).
        __syncthreads();
    }

    const int cr = (l >> 4) * 4, cc = l & 15;
    float* pbase = C + (size_t)z * M * N;        // EP_PARTIAL
#pragma unroll
    for (int m = 0; m < 8; m++) {
#pragma unroll
        for (int j = 0; j < 4; j++) {
            const int row = m0 + wr * 128 + m * 16 + cr + j;
#pragma unroll
            for (int n = 0; n < 4; n++) {
                const int col = n0 + wc * 64 + n * 16 + cc;
                float v = acc[m][n][j];
                if (MODE == EP_SPLIT_SILU) {
                    v += bias[col];
                    if (col < Esplit)
                        C[(size_t)row * Esplit + col] = v;
                    else
                        out2[(size_t)row * Esplit + (col - Esplit)] = silu_f(v);
                } else {  // EP_PARTIAL
                    if (col < N) pbase[(size_t)row * N + col] = v;
                }
            }
        }
    }
}

// ---- shared 128x128 bf16 MFMA GEMM body (g3), single 32KB buffer ----
template <int MODE>
__device__ __forceinline__ void gemm_body(
    const ushort* __restrict__ A, const ushort* __restrict__ Bt,
    float* __restrict__ C, const float* __restrict__ bias,
    float* __restrict__ out2, int M, int N, int K, int Esplit, int KS)
{
    __shared__ ushort As[128 * 64];
    __shared__ ushort Bs[128 * 64];
    const int tid = threadIdx.x;
    const int w = tid >> 6, l = tid & 63;
    const int wr = w >> 1, wc = w & 1;
    const int m0 = blockIdx.y * 128, n0 = blockIdx.x * 128;
    const int z = blockIdx.z;
    const int kbeg = z * KS;
    const int nt = KS / 64;
    const int srow = l >> 3, scol = (l & 7) * 8;
    const int fr = l & 15, kc = (l >> 4) * 8;

    f32x4 acc[4][4];
#pragma unroll
    for (int m = 0; m < 4; m++)
#pragma unroll
        for (int n = 0; n < 4; n++) acc[m][n] = (f32x4)(0.f);

    for (int t = 0; t < nt; t++) {
        const int k0 = kbeg + t * 64;
#pragma unroll
        for (int r = 0; r < 4; r++) {
            const int row = r * 32 + w * 8 + srow;
            int brow = n0 + row; if (brow > N - 1) brow = N - 1;
            gload16(A + (size_t)(m0 + row) * K + k0 + scol,
                    &As[r * 2048 + w * 512]);
            gload16(Bt + (size_t)brow * K + k0 + scol,
                    &Bs[r * 2048 + w * 512]);
        }
        __syncthreads();
#pragma unroll
        for (int kk = 0; kk < 64; kk += 32) {
            bf16x8 af[4], bfr[4];
#pragma unroll
            for (int m = 0; m < 4; m++)
                af[m] = *(const bf16x8*)&As[(wr * 64 + m * 16 + fr) * 64 + kk + kc];
#pragma unroll
            for (int n = 0; n < 4; n++)
                bfr[n] = *(const bf16x8*)&Bs[(wc * 64 + n * 16 + fr) * 64 + kk + kc];
#pragma unroll
            for (int m = 0; m < 4; m++)
#pragma unroll
                for (int n = 0; n < 4; n++)
                    acc[m][n] = __builtin_amdgcn_mfma_f32_16x16x32_bf16(
                        af[m], bfr[n], acc[m][n], 0, 0, 0);
        }
        __syncthreads();
    }

    const int cr = (l >> 4) * 4, cc = l & 15;
    float* pbase = C + (size_t)z * M * N;
#pragma unroll
    for (int m = 0; m < 4; m++) {
#pragma unroll
        for (int j = 0; j < 4; j++) {
            const int row = m0 + wr * 64 + m * 16 + cr + j;
#pragma unroll
            for (int n = 0; n < 4; n++) {
                const int col = n0 + wc * 64 + n * 16 + cc;
                float v = acc[m][n][j];
                if (MODE == EP_BIAS) {
                    C[(size_t)row * N + col] = v + bias[col];
                } else {  // EP_PARTIAL
                    if (col < N) pbase[(size_t)row * N + col] = v;
                }
            }
        }
    }
}

__global__ __launch_bounds__(256) void g3_gemm(
    const ushort* __restrict__ A, const ushort* __restrict__ Bt,
    float* __restrict__ C, int M, int N, int K, int KS)
{ gemm_body<EP_PARTIAL>(A, Bt, C, nullptr, nullptr, M, N, K, 0, KS); }

// ---- GEMM4: K=128, single-buffer; pure GEMM -> bf16 raw (v + bias) ----
__global__ __launch_bounds__(256) void g4_gemm(
    const ushort* __restrict__ A, const ushort* __restrict__ Bt,
    ushort* __restrict__ draw, const float* __restrict__ bias, int M, int N)
{
    __shared__ ushort As[128 * 64];
    __shared__ ushort Bs[128 * 64];
    const int tid = threadIdx.x;
    const int w = tid >> 6, l = tid & 63;
    const int wr = w >> 1, wc = w & 1;
    const int m0 = blockIdx.y * 128, n0 = blockIdx.x * 128;
    const int srow = l >> 3, scol = (l & 7) * 8;
    const int K = 128;

    f32x4 acc[4][4];
#pragma unroll
    for (int m = 0; m < 4; m++)
#pragma unroll
        for (int n = 0; n < 4; n++) acc[m][n] = (f32x4)(0.f);

    const int fr = l & 15, kc = (l >> 4) * 8;
#pragma unroll
    for (int t = 0; t < 2; t++) {
        const int k0 = t * 64;
#pragma unroll
        for (int r = 0; r < 4; r++) {
            const int row = r * 32 + w * 8 + srow;
            gload16(A + (size_t)(m0 + row) * K + k0 + scol, &As[r * 2048 + w * 512]);
            gload16(Bt + (size_t)(n0 + row) * K + k0 + scol, &Bs[r * 2048 + w * 512]);
        }
        __syncthreads();
#pragma unroll
        for (int kk = 0; kk < 64; kk += 32) {
            bf16x8 af[4], bfr[4];
#pragma unroll
            for (int m = 0; m < 4; m++)
                af[m] = *(const bf16x8*)&As[(wr * 64 + m * 16 + fr) * 64 + kk + kc];
#pragma unroll
            for (int n = 0; n < 4; n++)
                bfr[n] = *(const bf16x8*)&Bs[(wc * 64 + n * 16 + fr) * 64 + kk + kc];
#pragma unroll
            for (int m = 0; m < 4; m++)
#pragma unroll
                for (int n = 0; n < 4; n++)
                    acc[m][n] = __builtin_amdgcn_mfma_f32_16x16x32_bf16(
                        af[m], bfr[n], acc[m][n], 0, 0, 0);
        }
        __syncthreads();
    }

    const int cr = (l >> 4) * 4, cc = l & 15;
#pragma unroll
    for (int m = 0; m < 4; m++) {
#pragma unroll
        for (int j = 0; j < 4; j++) {
            const int row = m0 + wr * 64 + m * 16 + cr + j;
#pragma unroll
            for (int n = 0; n < 4; n++) {
                const int col = n0 + wc * 64 + n * 16 + cc;
                draw[(size_t)row * N + col] = f2bf(acc[m][n][j] + bias[col]);
            }
        }
    }
}

// Reduce split-K partials -> proj fp32; also emit dt columns (<128) as bf16.
__global__ __launch_bounds__(256) void gemm3_reduce(
    const float* __restrict__ Pp, float* __restrict__ proj,
    ushort* __restrict__ dtbf, int M, int N, int Z)
{
    const size_t g = (size_t)blockIdx.x * 256 + threadIdx.x;
    const size_t tot = (size_t)M * N;
    if (g >= tot) return;
    float s = 0.f;
    for (int z = 0; z < Z; z++) s += Pp[(size_t)z * tot + g];
    proj[g] = s;
    const int col = (int)(g % N);
    if (col < 128) {
        const size_t row = g / N;
        dtbf[row * 128 + col] = f2bf(s);
    }
}

// Reduce GEMM6 split-K(Z) partials + bias -> out fp32 (float4).
__global__ __launch_bounds__(256) void reduce6(
    const float* __restrict__ Pp, const float* __restrict__ bias,
    float* __restrict__ out, int M, int N, int Z)
{
    const size_t g = (size_t)blockIdx.x * 256 + threadIdx.x;
    const size_t tot4 = (size_t)M * N / 4;
    if (g >= tot4) return;
    const int n4 = N / 4;
    float4 s = ((const float4*)bias)[g % n4];
    for (int z = 0; z < Z; z++) {
        float4 p = ((const float4*)Pp)[z * tot4 + g];
        s.x += p.x; s.y += p.y; s.z += p.z; s.w += p.w;
    }
    ((float4*)out)[g] = s;
}

// fp32 -> bf16 copy (vectorized)
__global__ __launch_bounds__(256) void f2bf_vec(
    const float* __restrict__ in, ushort* __restrict__ out, size_t n4)
{
    for (size_t i = (size_t)blockIdx.x * 256 + threadIdx.x; i < n4;
         i += (size_t)gridDim.x * 256) {
        float4 v = ((const float4*)in)[i];
        ushort4 o;
        o.x = f2bf(v.x); o.y = f2bf(v.y); o.z = f2bf(v.z); o.w = f2bf(v.w);
        ((ushort4*)out)[i] = o;
    }
}

// W (R x Ccols) fp32 -> Wt (Ccols x R) bf16, tiled transpose
__global__ __launch_bounds__(256) void f2bf_transpose(
    const float* __restrict__ W, ushort* __restrict__ Wt, int R, int Ccols)
{
    __shared__ float tile[32][33];
    const int bc = blockIdx.x * 32, br = blockIdx.y * 32;
    const int tx = threadIdx.x & 31, ty = threadIdx.x >> 5;
    for (int i = ty; i < 32; i += 8)
        tile[i][tx] = W[(size_t)(br + i) * Ccols + bc + tx];
    __syncthreads();
    for (int i = ty; i < 32; i += 8)
        Wt[(size_t)(bc + i) * R + br + tx] = f2bf(tile[tx][i]);
}

// Depthwise causal conv (K=4) + bias + SiLU; 4 ch/thread; bf16 output only.
__global__ __launch_bounds__(256) void conv_silu4(
    const float* __restrict__ xin, const float* __restrict__ w,
    const float* __restrict__ cb, ushort* __restrict__ xobf,
    int Ln, int En, size_t total4)
{
    const int Eq = En >> 2;
    for (size_t idx = (size_t)blockIdx.x * 256 + threadIdx.x; idx < total4;
         idx += (size_t)gridDim.x * 256) {
        const int e4 = (int)(idx % Eq);
        const size_t row = idx / Eq;
        const int l = (int)(row % Ln);
        float4 acc = ((const float4*)cb)[e4];
        const float4 w0 = ((const float4*)w)[e4 * 4 + 0];
        const float4 w1 = ((const float4*)w)[e4 * 4 + 1];
        const float4 w2 = ((const float4*)w)[e4 * 4 + 2];
        const float4 w3 = ((const float4*)w)[e4 * 4 + 3];
        const float wt0[4] = {w0.x, w0.y, w0.z, w0.w};
        const float wt1[4] = {w1.x, w1.y, w1.z, w1.w};
        const float wt2[4] = {w2.x, w2.y, w2.z, w2.w};
        const float wt3[4] = {w3.x, w3.y, w3.z, w3.w};
#pragma unroll
        for (int k = 0; k < 4; k++) {
            if (l - 3 + k >= 0) {
                float4 xv = ((const float4*)xin)[(row - 3 + k) * Eq + e4];
                acc.x = fmaf(wt0[k], xv.x, acc.x);
                acc.y = fmaf(wt1[k], xv.y, acc.y);
                acc.z = fmaf(wt2[k], xv.z, acc.z);
                acc.w = fmaf(wt3[k], xv.w, acc.w);
            }
        }
        ushort4 o;
        o.x = f2bf(silu_f(acc.x)); o.y = f2bf(silu_f(acc.y));
        o.z = f2bf(silu_f(acc.z)); o.w = f2bf(silu_f(acc.w));
        ((ushort4*)xobf)[idx] = o;
    }
}

// ---- Chunked parallel selective scan (delta raw bf16 + softplus here; u bf16) ----
__global__ __launch_bounds__(256) void scan_pass1(
    const ushort* __restrict__ draw, const ushort* __restrict__ u,
    const float* __restrict__ proj, const float* __restrict__ A_log,
    float* __restrict__ Pbuf, float* __restrict__ Sbuf)
{
    __shared__ float sB[ST * SN];
    const int tid = threadIdx.x;
    const int eb = blockIdx.x & 7;
    const int c  = (blockIdx.x >> 3) & (SC - 1);
    const int b  = blockIdx.x >> 9;
    const int e  = eb * 256 + tid;
    const size_t row0 = (size_t)b * SL + c * ST;

    for (int i = tid; i < ST * SN; i += 256) {
        const int tl = i >> 4, n = i & 15;
        sB[i] = proj[(row0 + tl) * 160 + 128 + n];
    }
    __syncthreads();

    float An[SN], h[SN];
    {
        const float4* Ap = (const float4*)(A_log + (size_t)e * SN);
#pragma unroll
        for (int q = 0; q < 4; q++) {
            float4 v = Ap[q];
            An[q * 4 + 0] = -expf(v.x);
            An[q * 4 + 1] = -expf(v.y);
            An[q * 4 + 2] = -expf(v.z);
            An[q * 4 + 3] = -expf(v.w);
        }
    }
#pragma unroll
    for (int n = 0; n < SN; n++) h[n] = 0.f;

    float dsum = 0.f;
    size_t idx = row0 * SE + e;
    float d = softplus_f(bf2f(draw[idx])), uu = bf2f(u[idx]);
    for (int tl = 0; tl < ST; tl++) {
        ushort dn = 0, un = 0;
        if (tl + 1 < ST) { dn = draw[idx + SE]; un = u[idx + SE]; }
        const float du = d * uu;
        dsum += d;
#pragma unroll
        for (int n = 0; n < SN; n++) {
            const float dA = __expf(d * An[n]);
            h[n] = fmaf(dA, h[n], du * sB[tl * SN + n]);
        }
        d = softplus_f(bf2f(dn)); uu = bf2f(un); idx += SE;
    }

    const size_t ob = ((((size_t)c * SB) + b) * SE + e) * SN;
#pragma unroll
    for (int q = 0; q < 4; q++) {
        float4 pv, sv;
        pv.x = __expf(An[q * 4 + 0] * dsum); sv.x = h[q * 4 + 0];
        pv.y = __expf(An[q * 4 + 1] * dsum); sv.y = h[q * 4 + 1];
        pv.z = __expf(An[q * 4 + 2] * dsum); sv.z = h[q * 4 + 2];
        pv.w = __expf(An[q * 4 + 3] * dsum); sv.w = h[q * 4 + 3];
        *(float4*)(Pbuf + ob + q * 4) = pv;
        *(float4*)(Sbuf + ob + q * 4) = sv;
    }
}

__global__ __launch_bounds__(256) void scan_pass2(
    const float* __restrict__ Pbuf, const float* __restrict__ Sbuf,
    float* __restrict__ hinit)
{
    const size_t g = (size_t)blockIdx.x * 256 + threadIdx.x;
    const size_t stride = (size_t)SB * SE * SN;
    float h = 0.f;
    float P = Pbuf[g], S = Sbuf[g];
    for (int c = 0; c < SC; c++) {
        float Pn = 0.f, Sn = 0.f;
        if (c + 1 < SC) {
            Pn = Pbuf[(c + 1) * stride + g];
            Sn = Sbuf[(c + 1) * stride + g];
        }
        hinit[c * stride + g] = h;
        h = fmaf(P, h, S);
        P = Pn; S = Sn;
    }
}

__global__ __launch_bounds__(256) void scan_pass3(
    const ushort* __restrict__ draw, const ushort* __restrict__ u,
    const float* __restrict__ proj, const float* __restrict__ A_log,
    const float* __restrict__ Dp, const float* __restrict__ xr,
    const float* __restrict__ hinit, ushort* __restrict__ yg)
{
    __shared__ float sB[ST * SN];
    __shared__ float sC[ST * SN];
    const int tid = threadIdx.x;
    const int eb = blockIdx.x & 7;
    const int c  = (blockIdx.x >> 3) & (SC - 1);
    const int b  = blockIdx.x >> 9;
    const int e  = eb * 256 + tid;
    const size_t row0 = (size_t)b * SL + c * ST;

    for (int i = tid; i < ST * SN; i += 256) {
        const int tl = i >> 4, n = i & 15;
        sB[i] = proj[(row0 + tl) * 160 + 128 + n];
        sC[i] = proj[(row0 + tl) * 160 + 144 + n];
    }
    __syncthreads();

    float An[SN], h[SN];
    {
        const float4* Ap = (const float4*)(A_log + (size_t)e * SN);
#pragma unroll
        for (int q = 0; q < 4; q++) {
            float4 v = Ap[q];
            An[q * 4 + 0] = -expf(v.x);
            An[q * 4 + 1] = -expf(v.y);
            An[q * 4 + 2] = -expf(v.z);
            An[q * 4 + 3] = -expf(v.w);
        }
    }
    {
        const size_t ib = ((((size_t)c * SB) + b) * SE + e) * SN;
#pragma unroll
        for (int q = 0; q < 4; q++) {
            float4 v = *(const float4*)(hinit + ib + q * 4);
            h[q * 4 + 0] = v.x; h[q * 4 + 1] = v.y;
            h[q * 4 + 2] = v.z; h[q * 4 + 3] = v.w;
        }
    }
    const float De = Dp[e];

    size_t idx = row0 * SE + e;
    float d = softplus_f(bf2f(draw[idx])), uu = bf2f(u[idx]), g = xr[idx];
    for (int tl = 0; tl < ST; tl++) {
        ushort dn = 0, un = 0;
        float gn = 0.f;
        if (tl + 1 < ST) {
            dn = draw[idx + SE]; un = u[idx + SE]; gn = xr[idx + SE];
        }
        const float du = d * uu;
        float y = 0.f;
#pragma unroll
        for (int n = 0; n < SN; n++) {
            const float dA = __expf(d * An[n]);
            h[n] = fmaf(dA, h[n], du * sB[tl * SN + n]);
            y = fmaf(h[n], sC[tl * SN + n], y);
        }
        yg[idx] = f2bf((y + uu * De) * g);
        d = softplus_f(bf2f(dn)); uu = bf2f(un); g = gn; idx += SE;
    }
}

extern "C" void kernel_launch(void* const* d_in, const int* in_sizes, int n_in,
                              void* d_out, int out_size, void* d_ws, size_t ws_size,
                              hipStream_t stream)
{
    const int Bc = 2, Lc = 2048, Hc = 1024, Ec = 2048;
    const int M = Bc * Lc;      // 4096
    const int PN = 160;
    const int SKZ = 8;          // GEMM3 split-K
    const int SK6 = 4;          // GEMM6 split-K (256^2: 4x16x4 = 256 blocks)

    const float* x        = (const float*)d_in[0];
    const float* W_in     = (const float*)d_in[1];
    const float* b_in     = (const float*)d_in[2];
    const float* conv_w   = (const float*)d_in[3];
    const float* conv_b   = (const float*)d_in[4];
    const float* x_proj_w = (const float*)d_in[5];
    const float* dt_proj_w= (const float*)d_in[6];
    const float* dt_bias  = (const float*)d_in[7];
    const float* A_log    = (const float*)d_in[8];
    const float* D_param  = (const float*)d_in[9];
    const float* W_out    = (const float*)d_in[10];
    const float* b_out    = (const float*)d_in[11];
    float* out = (float*)d_out;

    float* ws = (float*)d_ws;
    const size_t ME = (size_t)M * Ec;            // 8,388,608 floats
    const size_t PS = (size_t)SB * SE * SC * SN; // 4,194,304 floats

    // region map (floats):
    float* xc_raw = ws;                  // R0: g1 z-out (conv input) / Pp3 / P,S / ygbf
    float* xr     = xc_raw + ME;         // R1: xr gate -> Pp6 (spans R1+R2) after pass3
    float* r2     = xr + ME;             // R2: W_in_t early -> xc_bf (conv out)
    float* r3     = r2 + ME;             // R3: xbf early -> draw (bf16) -> W_out_t
    float* proj   = r3 + ME;
    float* hinit  = proj + (size_t)M * PN;  // also hosts xpw_t/dtw_t/dtbf pre-pass2

    ushort* xbf    = (ushort*)r3;            // dead after g1
    ushort* W_in_t = (ushort*)r2;            // dead after g1
    ushort* xc_bf  = (ushort*)r2;            // conv bf16 out; u for g3+scans
    ushort* draw   = (ushort*)r3;            // g4 raw bf16 out (16.7MB)
    float*  Pp3    = xc_raw;                 // SKZ*M*160 = 5.24M floats
    ushort* xpw_t  = (ushort*)hinit;
    ushort* dtw_t  = (ushort*)hinit + 327680;
    ushort* dtbf   = (ushort*)hinit + 327680 + 262144;
    float*  Pbuf   = xc_raw;
    float*  Sbuf   = xc_raw + PS;
    ushort* ygbf   = (ushort*)xc_raw;
    ushort* W_out_t= (ushort*)r3;            // after pass3 (draw dead)
    float*  Pp6    = xr;                     // SK6*M*1024 = 16.78M fl = R1+R2 (dead)

    // 0) dtype conversions / weight transposes
    f2bf_vec<<<1024, 256, 0, stream>>>(x, xbf, (size_t)M * Hc / 4);
    f2bf_transpose<<<dim3(2 * Ec / 32, Hc / 32), 256, 0, stream>>>(
        W_in, W_in_t, Hc, 2 * Ec);
    f2bf_transpose<<<dim3(PN / 32, Ec / 32), 256, 0, stream>>>(
        x_proj_w, xpw_t, Ec, PN);
    f2bf_transpose<<<dim3(Ec / 32, 128 / 32), 256, 0, stream>>>(
        dt_proj_w, dtw_t, 128, Ec);

    // 1) z = x @ W_in + b_in ; split -> xc_raw (fp32), silu -> xr (fp32)
    //    8-phase 256^2, grid 16x16 = 256 blocks (1/CU, 128KB LDS)
    hgemm8p<EP_SPLIT_SILU><<<dim3(2 * Ec / 256, M / 256, 1), 512, 0, stream>>>(
        xbf, W_in_t, xc_raw, b_in, xr, M, 2 * Ec, Hc, Ec, Hc);

    // 2) depthwise causal conv + bias + silu -> xc_bf (bf16 only)
    conv_silu4<<<2048, 256, 0, stream>>>(
        xc_raw, conv_w, conv_b, xc_bf, Lc, Ec, ME / 4);

    // 3) proj = xc @ x_proj_w : split-K bf16 MFMA + reduce (emits dt bf16 too)
    g3_gemm<<<dim3(2, M / 128, SKZ), 256, 0, stream>>>(
        xc_bf, xpw_t, Pp3, M, PN, Ec, Ec / SKZ);
    gemm3_reduce<<<(M * PN + 255) / 256, 256, 0, stream>>>(
        Pp3, proj, dtbf, M, PN, SKZ);

    // 4) draw = dt @ dt_proj_w + dt_bias (bf16 raw; softplus in scans)
    g4_gemm<<<dim3(Ec / 128, M / 128), 256, 0, stream>>>(
        dtbf, dtw_t, draw, dt_bias, M, Ec);

    // 5) chunked parallel scan; pass3 emits bf16 yg
    scan_pass1<<<SB * SC * (SE / 256), 256, 0, stream>>>(
        draw, xc_bf, proj, A_log, Pbuf, Sbuf);
    scan_pass2<<<(SB * SE * SN) / 256, 256, 0, stream>>>(Pbuf, Sbuf, hinit);
    scan_pass3<<<SB * SC * (SE / 256), 256, 0, stream>>>(
        draw, xc_bf, proj, A_log, D_param, xr, hinit, ygbf);

    // 5b) W_out (E x H) -> bf16 (H x E)  (draw dead now)
    f2bf_transpose<<<dim3(Hc / 32, Ec / 32), 256, 0, stream>>>(
        W_out, W_out_t, Ec, Hc);

    // 6) out = yg @ W_out : 8-phase 256^2, split-K=4 + bias reduce
    hgemm8p<EP_PARTIAL><<<dim3(Hc / 256, M / 256, SK6), 512, 0, stream>>>(
        ygbf, W_out_t, Pp6, nullptr, nullptr, M, Hc, Ec, 0, Ec / SK6);
    reduce6<<<(int)((size_t)M * Hc / 4 + 255) / 256, 256, 0, stream>>>(
        Pp6, b_out, out, M, Hc, SK6);
}